// Round 10
// baseline (153.245 us; speedup 1.0000x reference)
//
#include <hip/hip_runtime.h>
#include <math.h>

// Problem constants
#define BATCH 8192
#define LOD 60
#define LSD 120
#define AD 10
#define NB 15
#define BW 3
#define H 60

// Output layout (floats)
#define NM_SZ (BATCH * LSD)   // next_mean 983040
#define NC_SZ (BATCH * LOD)   // 491520 each for ncu/ncl/ncs

// Workspace layout (floats):
//   tmbg  @ 0      : [60][448] banded tm pack (64B-aligned rows for s_load)
//   coef_t@ 26880  : [15][8192] softmaxed mixture coefs, transposed
//   ctrl_t@ 149760 : [120][8192] control rows, transposed
// total 1132800 floats = 4.53 MB (same footprint as the passing r0 baseline)
#define TMBG_STRIDE 448
#define TMBG_ROW 420                      // NB*7*4 valid floats per row
#define TMBG_FLOATS (LOD * TMBG_STRIDE)   // 26880 = 105 * 256
#define WS_COEF TMBG_FLOATS
#define WS_CTRL (WS_COEF + NB * BATCH)    // 149760

// Main-kernel geometry: 128 bg (64 batches) x 8 rg (8 rows) = 1024 blocks.
#define RGS 8
#define RG_ROWS 8
#define NJJ 16                        // 8 + 2*BW = 14, padded to pow2
#define VSJ 65
#define VSV (NJJ * VSJ)               // 1040 floats per staged plane
#define VS_FLOATS (5 * VSV)           // 5200 floats = 20.8 KB (only LDS in main)
#define OST_PLANE (RG_ROWS * 65)      // 520; ost (2600) overlays vs after bar2

typedef float v2f __attribute__((ext_vector_type(2)));
#define FMA2(a, b, c) __builtin_elementwise_fma((a), (b), (c))

__device__ __forceinline__ float elup1f(float x) {
    return x < 0.0f ? __expf(x) : x + 1.0f;
}

// ---------------------------------------------------------------------------
// Prepass (256 thr / 4 waves — proven config):
//   blocks [0,128):    per-bg coef softmax + control MLP -> ws (transposed)
//   blocks [128,233):  banded tm pack -> tmbg (105*256 = 26880 exactly)
// ---------------------------------------------------------------------------
__global__ __launch_bounds__(256) void k_prep(
    const float* __restrict__ pm, const float* __restrict__ action,
    const float* __restrict__ tm11, const float* __restrict__ tm12,
    const float* __restrict__ tm21, const float* __restrict__ tm22,
    const float* __restrict__ w_coef, const float* __restrict__ b_coef,
    const float* __restrict__ w_c1, const float* __restrict__ b_c1,
    const float* __restrict__ w_c2, const float* __restrict__ b_c2,
    float* __restrict__ ws)
{
    const int tid = threadIdx.x;
    const int bid = blockIdx.x;

    if (bid >= 128) {                    // ---- banded tm pack ----
        int idx = (bid - 128) * 256 + tid;
        if (idx < TMBG_FLOATS) {
            int i = idx / TMBG_STRIDE;
            int r = idx - i * TMBG_STRIDE;
            float val = 0.0f;
            if (r < TMBG_ROW) {
                int k  = r / 28;
                int z  = r - k * 28;
                int jo = z >> 2;
                int m  = z & 3;
                int j  = i - BW + jo;
                const float* tmm = (m == 0) ? tm11 : (m == 1) ? tm12
                                 : (m == 2) ? tm21 : tm22;
                if (j >= 0 && j < LOD) val = tmm[k * (LOD * LOD) + i * LOD + j];
            }
            ws[idx] = val;
        }
        return;                          // block-uniform: no barrier skipped
    }

    // ---- coef + control for 64 batches (proven round-5 phase-A blocks) ----
    __shared__ float lg_s[NB * 64];      // [k][b]
    __shared__ float hid_s[H * 65];      // [h][b] stride 65

    const int lane = tid & 63;
    const int wv   = __builtin_amdgcn_readfirstlane(tid >> 6);  // 0..3
    const int b0   = bid * 64;

    // logits: per-lane float4 stream (L1-resident tile), wave-uniform weights
    {
        const int k0 = wv, k1 = wv + 4, k2 = wv + 8;
        const int k3 = (wv < 3) ? wv + 12 : 14;      // wave 3: dummy stream
        const float4* pmv = (const float4*)(pm + (size_t)(b0 + lane) * LSD);
        const float4* w0 = (const float4*)(w_coef + k0 * LSD);
        const float4* w1 = (const float4*)(w_coef + k1 * LSD);
        const float4* w2 = (const float4*)(w_coef + k2 * LSD);
        const float4* w3 = (const float4*)(w_coef + k3 * LSD);
        v2f a0 = {0.f, 0.f}, a1 = {0.f, 0.f}, a2 = {0.f, 0.f}, a3 = {0.f, 0.f};
        #pragma unroll 6
        for (int d = 0; d < LSD / 4; ++d) {
            float4 p = pmv[d];
            v2f plo = {p.x, p.y}, phi = {p.z, p.w};
            float4 u0 = w0[d], u1 = w1[d], u2 = w2[d], u3 = w3[d];
            a0 = FMA2(plo, ((v2f){u0.x, u0.y}), a0);
            a0 = FMA2(phi, ((v2f){u0.z, u0.w}), a0);
            a1 = FMA2(plo, ((v2f){u1.x, u1.y}), a1);
            a1 = FMA2(phi, ((v2f){u1.z, u1.w}), a1);
            a2 = FMA2(plo, ((v2f){u2.x, u2.y}), a2);
            a2 = FMA2(phi, ((v2f){u2.z, u2.w}), a2);
            a3 = FMA2(plo, ((v2f){u3.x, u3.y}), a3);
            a3 = FMA2(phi, ((v2f){u3.z, u3.w}), a3);
        }
        lg_s[k0 * 64 + lane] = a0.x + a0.y + b_coef[k0];
        lg_s[k1 * 64 + lane] = a1.x + a1.y + b_coef[k1];
        lg_s[k2 * 64 + lane] = a2.x + a2.y + b_coef[k2];
        if (wv < 3) lg_s[k3 * 64 + lane] = a3.x + a3.y + b_coef[k3];
    }
    // hidden: wave wv owns h in [15wv, 15wv+15)
    {
        v2f av2[5];
        const float2* a2p = (const float2*)(action + (size_t)(b0 + lane) * AD);
        #pragma unroll
        for (int z = 0; z < 5; ++z) { float2 t2 = a2p[z]; av2[z] = (v2f){t2.x, t2.y}; }
        #pragma unroll
        for (int q = 0; q < 15; ++q) {
            int h = wv * 15 + q;
            v2f acc2 = {0.f, 0.f};
            #pragma unroll
            for (int z = 0; z < 5; ++z)
                acc2 = FMA2(av2[z], *(const v2f*)(w_c1 + h * AD + 2 * z), acc2);
            float acc = acc2.x + acc2.y + b_c1[h];
            hid_s[h * 65 + lane] = fmaxf(acc, 0.0f);
        }
    }
    __syncthreads();   // bar1: logits + hidden visible

    // softmax -> coef_t (wave 0; other waves proceed to control)
    if (tid < 64) {
        float v[NB];
        float mx = -1e30f;
        #pragma unroll
        for (int k = 0; k < NB; ++k) { v[k] = lg_s[k * 64 + tid]; mx = fmaxf(mx, v[k]); }
        float sm = 0.0f;
        #pragma unroll
        for (int k = 0; k < NB; ++k) { v[k] = __expf(v[k] - mx); sm += v[k]; }
        float inv = 1.0f / sm;
        #pragma unroll
        for (int k = 0; k < NB; ++k) ws[WS_COEF + k * BATCH + b0 + tid] = v[k] * inv;
    }

    // control: wave wv owns 30 output rows o in [30wv, 30wv+30); batch = lane.
    // h-outer: hid_s read lane-stride-1; w_c2 reads wave-uniform -> s_load.
    {
        float acc[30];
        #pragma unroll
        for (int q = 0; q < 30; ++q) acc[q] = b_c2[wv * 30 + q];
        for (int h = 0; h < H; ++h) {
            float hv = hid_s[h * 65 + lane];
            #pragma unroll
            for (int q = 0; q < 30; ++q)
                acc[q] = fmaf(hv, w_c2[(wv * 30 + q) * H + h], acc[q]);
        }
        #pragma unroll
        for (int q = 0; q < 30; ++q)
            ws[WS_CTRL + (wv * 30 + q) * BATCH + b0 + lane] = acc[q];
    }
}

// ---------------------------------------------------------------------------
// Main kernel (round-7 proven core): banded predict. Per-batch MLP results
// come from ws as coalesced loads; mixing weights via uniform scalar loads.
// ---------------------------------------------------------------------------
__global__ __launch_bounds__(256, 4) void k_main(
    const float* __restrict__ pm, const float* __restrict__ cu,
    const float* __restrict__ cl, const float* __restrict__ cs,
    const float* __restrict__ log_noise,
    const float* __restrict__ ws,        // tmbg / coef_t / ctrl_t
    float* __restrict__ out)
{
    __shared__ __align__(16) float vsb[VS_FLOATS];   // 20.8 KB only

    const int tid  = threadIdx.x;
    const int lane = tid & 63;
    const int wv   = __builtin_amdgcn_readfirstlane(tid >> 6);

    // XCD-grouped swizzle: the 8 rg-blocks of one bg share one XCD's L2.
    const int bid  = blockIdx.x;            // 1024 = 8 XCDs * 128
    const int xcd  = bid & 7;
    const int slot = bid >> 3;              // 0..127
    const int bg   = xcd * 16 + (slot >> 3);
    const int rg   = slot & 7;
    const int b0   = bg * 64;
    const int i0   = rg * RG_ROWS;
    const int b    = b0 + lane;

    const float* coef_t = ws + WS_COEF;
    const float* ctrl_t = ws + WS_CTRL;

    // ---------------- issue ALL global loads up front (T14) ----------------
    float cf[NB];
    #pragma unroll
    for (int k = 0; k < NB; ++k) cf[k] = coef_t[k * BATCH + b];   // coalesced

    const int r0g = i0 + 2 * wv;
    const int c0  = (r0g < LOD) ? r0g : LOD - 1;        // rg7/wv3 clamp
    const int c1  = (r0g + 1 < LOD) ? r0g + 1 : LOD - 1;
    float ctl0 = ctrl_t[c0 * BATCH + b];                 // coalesced
    float ctl1 = ctrl_t[c1 * BATCH + b];
    float ctl2 = ctrl_t[(LOD + c0) * BATCH + b];
    float ctl3 = ctrl_t[(LOD + c1) * BATCH + b];

    float vr[20];
    {
        const int jj  = tid & 15;
        const int j   = i0 - BW + jj;
        const bool jok = (j >= 0) && (j < LOD);
        #pragma unroll
        for (int z = 0; z < 20; ++z) {
            const int idx = z * 256 + tid;
            const int blc = (idx >> 4) & 63;
            const int bb  = b0 + blc;
            float val = 0.0f;
            if (jok) {
                const int v = z >> 2;                  // compile-time per z
                if (v == 0)      val = pm[bb * LSD + j];
                else if (v == 1) val = pm[bb * LSD + LOD + j];
                else if (v == 2) val = cu[bb * LOD + j];
                else if (v == 3) val = cl[bb * LOD + j];
                else             val = cs[bb * LOD + j];
            }
            vr[z] = val;
        }
    }

    // ---------------- vs LDS writes ----------------------------------------
    {
        const int jj = tid & 15;
        #pragma unroll
        for (int z = 0; z < 20; ++z) {
            const int idx = z * 256 + tid;
            const int blc = (idx >> 4) & 63;
            vsb[(z >> 2) * VSV + jj * VSJ + blc] = vr[z];   // 2-way alias: free
        }
    }
    __syncthreads();   // bar1: vs staged

    // ---------------- mixing (scalar loads) + banded products --------------
    float onm[2], onl[2], ouv[2], olv[2], osv[2];
    #pragma unroll
    for (int rr = 0; rr < 2; ++rr) {
        const int riu = 2 * wv + rr;                    // wave-uniform
        const int iu  = i0 + riu;
        const int iuc = (iu < LOD) ? iu : LOD - 1;      // rg7: garbage, skipped

        const float* tpg = ws + (size_t)iuc * TMBG_STRIDE;
        v2f t2[14];
        #pragma unroll
        for (int z = 0; z < 14; ++z) t2[z] = (v2f){0.f, 0.f};
        #pragma unroll
        for (int k = 0; k < NB; ++k) {
            v2f c2 = {cf[k], cf[k]};                    // splat: free via op_sel
            #pragma unroll
            for (int jo = 0; jo < 7; ++jo) {
                v2f w01 = *(const v2f*)(tpg + k * 28 + jo * 4);      // s_load
                v2f w23 = *(const v2f*)(tpg + k * 28 + jo * 4 + 2);  // s_load
                t2[2 * jo]     = FMA2(c2, w01, t2[2 * jo]);
                t2[2 * jo + 1] = FMA2(c2, w23, t2[2 * jo + 1]);
            }
        }
        t2[6].x += 1.0f;     // + eye on t11 at jo == 3 (m=0)
        t2[7].y += 1.0f;     // + eye on t22 at jo == 3 (m=3)

        float nmu = 0.f, nml = 0.f, ncuv = 0.f, nclv = 0.f, ncsv = 0.f;
        #pragma unroll
        for (int jo = 0; jo < 7; ++jo) {
            const int jj = riu + jo;                    // 0..13 < NJJ
            float m_ = vsb[0 * VSV + jj * VSJ + lane];
            float n_ = vsb[1 * VSV + jj * VSJ + lane];
            float u_ = vsb[2 * VSV + jj * VSJ + lane];
            float l_ = vsb[3 * VSV + jj * VSJ + lane];
            float s_ = vsb[4 * VSV + jj * VSJ + lane];
            float A  = t2[2 * jo].x,     Bv = t2[2 * jo].y;
            float C  = t2[2 * jo + 1].x, D  = t2[2 * jo + 1].y;
            nmu = fmaf(A, m_, nmu);  nmu = fmaf(Bv, n_, nmu);
            nml = fmaf(C, m_, nml);  nml = fmaf(D, n_, nml);
            float e1 = fmaf(Bv, s_, A * u_);
            float e2 = fmaf(Bv, l_, A * s_);
            float f1 = fmaf(D, s_, C * u_);
            float f2 = fmaf(D, l_, C * s_);
            ncuv = fmaf(A, e1, ncuv);  ncuv = fmaf(Bv, e2, ncuv);
            nclv = fmaf(C, f1, nclv);  nclv = fmaf(D, f2, nclv);
            ncsv = fmaf(C, e1, ncsv);  ncsv = fmaf(D, e2, ncsv);
        }
        ncuv += elup1f(log_noise[iuc]);
        nclv += elup1f(log_noise[LOD + iuc]);
        nmu  += (rr == 0) ? ctl0 : ctl1;
        nml  += (rr == 0) ? ctl2 : ctl3;
        onm[rr] = nmu; onl[rr] = nml; ouv[rr] = ncuv; olv[rr] = nclv; osv[rr] = ncsv;
    }
    __syncthreads();   // bar2: all vs reads done -> overlay ost

    // ---------------- ost staging (overlays vs) + float4 flush -------------
    float* ost = vsb;
    #pragma unroll
    for (int rr = 0; rr < 2; ++rr) {
        const int ri = 2 * wv + rr;
        ost[0 * OST_PLANE + ri * 65 + lane] = onm[rr];
        ost[1 * OST_PLANE + ri * 65 + lane] = onl[rr];
        ost[2 * OST_PLANE + ri * 65 + lane] = ouv[rr];
        ost[3 * OST_PLANE + ri * 65 + lane] = olv[rr];
        ost[4 * OST_PLANE + ri * 65 + lane] = osv[rr];
    }
    __syncthreads();   // bar3

    // float4 flush: 640 stores total, 16B-aligned (i0 % 8 == 0)
    for (int idx = tid; idx < 5 * 64 * 2; idx += 256) {
        int q   = idx & 1;
        int blc = (idx >> 1) & 63;
        int t5  = idx >> 7;
        if (i0 + q * 4 + 3 >= LOD) continue;     // only rg7, q=1
        int bb = b0 + blc;
        int ro = q * 4;
        float4 v;
        v.x = ost[t5 * OST_PLANE + (ro + 0) * 65 + blc];
        v.y = ost[t5 * OST_PLANE + (ro + 1) * 65 + blc];
        v.z = ost[t5 * OST_PLANE + (ro + 2) * 65 + blc];
        v.w = ost[t5 * OST_PLANE + (ro + 3) * 65 + blc];
        float* bp;
        if (t5 == 0)      bp = out + bb * LSD + i0;
        else if (t5 == 1) bp = out + bb * LSD + LOD + i0;
        else if (t5 == 2) bp = out + NM_SZ + bb * LOD + i0;
        else if (t5 == 3) bp = out + NM_SZ + NC_SZ + bb * LOD + i0;
        else              bp = out + NM_SZ + 2 * NC_SZ + bb * LOD + i0;
        *(float4*)(bp + ro) = v;
    }
}

extern "C" void kernel_launch(void* const* d_in, const int* in_sizes, int n_in,
                              void* d_out, int out_size, void* d_ws, size_t ws_size,
                              hipStream_t stream) {
    (void)in_sizes; (void)n_in; (void)out_size; (void)ws_size;
    const float* pm        = (const float*)d_in[0];
    const float* cu        = (const float*)d_in[1];
    const float* cl        = (const float*)d_in[2];
    const float* cs        = (const float*)d_in[3];
    const float* action    = (const float*)d_in[4];
    const float* tm11      = (const float*)d_in[5];
    const float* tm12      = (const float*)d_in[6];
    const float* tm21      = (const float*)d_in[7];
    const float* tm22      = (const float*)d_in[8];
    const float* log_noise = (const float*)d_in[9];
    const float* w_coef    = (const float*)d_in[10];
    const float* b_coef    = (const float*)d_in[11];
    const float* w_c1      = (const float*)d_in[12];
    const float* b_c1      = (const float*)d_in[13];
    const float* w_c2      = (const float*)d_in[14];
    const float* b_c2      = (const float*)d_in[15];

    float* ws = (float*)d_ws;   // 1132800 floats = 4.53 MB

    hipLaunchKernelGGL(k_prep, dim3(128 + TMBG_FLOATS / 256), dim3(256), 0, stream,
                       pm, action, tm11, tm12, tm21, tm22,
                       w_coef, b_coef, w_c1, b_c1, w_c2, b_c2, ws);

    hipLaunchKernelGGL(k_main, dim3(1024), dim3(256), 0, stream,
                       pm, cu, cl, cs, log_noise, ws, (float*)d_out);
}

// Round 11
// 122.637 us; speedup vs baseline: 1.2496x; 1.2496x over previous
//
#include <hip/hip_runtime.h>
#include <math.h>

// Problem constants
#define BATCH 8192
#define LOD 60
#define LSD 120
#define AD 10
#define NB 15
#define BW 3
#define H 60

// Output layout (floats)
#define NM_SZ (BATCH * LSD)   // next_mean 983040
#define NC_SZ (BATCH * LOD)   // 491520 each for ncu/ncl/ncs

// Workspace layout (floats):
//   tmbg  @ 0      : [60][448] banded tm pack (64B-aligned rows for s_load)
//   coef_t@ 26880  : [15][8192] softmaxed mixture coefs, transposed
//   ctrl_t@ 149760 : [120][8192] control rows, transposed
#define TMBG_STRIDE 448
#define TMBG_ROW 420                      // NB*7*4 valid floats per row
#define TMBG_FLOATS (LOD * TMBG_STRIDE)   // 26880 = 105 * 256
#define WS_COEF TMBG_FLOATS
#define WS_CTRL (WS_COEF + NB * BATCH)    // 149760

// Main-kernel geometry: 128 bg (64 batches) x 8 rg (8 rows) = 1024 blocks.
#define RGS 8
#define RG_ROWS 8
#define NJJ 16                        // 8 + 2*BW = 14, padded to pow2
#define VSJ 65
#define VSV (NJJ * VSJ)               // 1040 floats per staged plane
#define VS_FLOATS (5 * VSV)           // 5200 floats = 20.8 KB (only LDS in main)
#define OST_PLANE (RG_ROWS * 65)      // 520; ost (2600) overlays vs after bar2

typedef float v2f __attribute__((ext_vector_type(2)));
#define FMA2(a, b, c) __builtin_elementwise_fma((a), (b), (c))

__device__ __forceinline__ float elup1f(float x) {
    return x < 0.0f ? __expf(x) : x + 1.0f;
}

// ---------------------------------------------------------------------------
// Prepass (256 thr / 4 waves):
//   blocks [0,128):    per-bg coef softmax + control MLP -> ws (transposed)
//   blocks [128,233):  banded tm pack -> tmbg (105*256 = 26880 exactly)
// Control phase is row-outer with hid in registers: NO accumulator arrays
// live across loop iterations -> no scratch demotion (r10: VGPR=20, 52 us).
// ---------------------------------------------------------------------------
__global__ __launch_bounds__(256) void k_prep(
    const float* __restrict__ pm, const float* __restrict__ action,
    const float* __restrict__ tm11, const float* __restrict__ tm12,
    const float* __restrict__ tm21, const float* __restrict__ tm22,
    const float* __restrict__ w_coef, const float* __restrict__ b_coef,
    const float* __restrict__ w_c1, const float* __restrict__ b_c1,
    const float* __restrict__ w_c2, const float* __restrict__ b_c2,
    float* __restrict__ ws)
{
    const int tid = threadIdx.x;
    const int bid = blockIdx.x;

    if (bid >= 128) {                    // ---- banded tm pack ----
        int idx = (bid - 128) * 256 + tid;
        if (idx < TMBG_FLOATS) {
            int i = idx / TMBG_STRIDE;
            int r = idx - i * TMBG_STRIDE;
            float val = 0.0f;
            if (r < TMBG_ROW) {
                int k  = r / 28;
                int z  = r - k * 28;
                int jo = z >> 2;
                int m  = z & 3;
                int j  = i - BW + jo;
                const float* tmm = (m == 0) ? tm11 : (m == 1) ? tm12
                                 : (m == 2) ? tm21 : tm22;
                if (j >= 0 && j < LOD) val = tmm[k * (LOD * LOD) + i * LOD + j];
            }
            ws[idx] = val;
        }
        return;                          // block-uniform: no barrier skipped
    }

    // ---- coef + control for 64 batches ----
    __shared__ float lg_s[NB * 64];      // [k][b]
    __shared__ float hid_s[H * 65];      // [h][b] stride 65

    const int lane = tid & 63;
    const int wv   = __builtin_amdgcn_readfirstlane(tid >> 6);  // 0..3
    const int b0   = bid * 64;

    // logits: per-lane float4 stream (L1/L2-resident tile), uniform weights
    {
        const int k0 = wv, k1 = wv + 4, k2 = wv + 8;
        const int k3 = (wv < 3) ? wv + 12 : 14;      // wave 3: dummy stream
        const float4* pmv = (const float4*)(pm + (size_t)(b0 + lane) * LSD);
        const float4* w0 = (const float4*)(w_coef + k0 * LSD);
        const float4* w1 = (const float4*)(w_coef + k1 * LSD);
        const float4* w2 = (const float4*)(w_coef + k2 * LSD);
        const float4* w3 = (const float4*)(w_coef + k3 * LSD);
        v2f a0 = {0.f, 0.f}, a1 = {0.f, 0.f}, a2 = {0.f, 0.f}, a3 = {0.f, 0.f};
        #pragma unroll 6
        for (int d = 0; d < LSD / 4; ++d) {
            float4 p = pmv[d];
            v2f plo = {p.x, p.y}, phi = {p.z, p.w};
            float4 u0 = w0[d], u1 = w1[d], u2 = w2[d], u3 = w3[d];
            a0 = FMA2(plo, ((v2f){u0.x, u0.y}), a0);
            a0 = FMA2(phi, ((v2f){u0.z, u0.w}), a0);
            a1 = FMA2(plo, ((v2f){u1.x, u1.y}), a1);
            a1 = FMA2(phi, ((v2f){u1.z, u1.w}), a1);
            a2 = FMA2(plo, ((v2f){u2.x, u2.y}), a2);
            a2 = FMA2(phi, ((v2f){u2.z, u2.w}), a2);
            a3 = FMA2(plo, ((v2f){u3.x, u3.y}), a3);
            a3 = FMA2(phi, ((v2f){u3.z, u3.w}), a3);
        }
        lg_s[k0 * 64 + lane] = a0.x + a0.y + b_coef[k0];
        lg_s[k1 * 64 + lane] = a1.x + a1.y + b_coef[k1];
        lg_s[k2 * 64 + lane] = a2.x + a2.y + b_coef[k2];
        if (wv < 3) lg_s[k3 * 64 + lane] = a3.x + a3.y + b_coef[k3];
    }
    // hidden: wave wv owns h in [15wv, 15wv+15)
    {
        v2f av2[5];
        const float2* a2p = (const float2*)(action + (size_t)(b0 + lane) * AD);
        #pragma unroll
        for (int z = 0; z < 5; ++z) { float2 t2 = a2p[z]; av2[z] = (v2f){t2.x, t2.y}; }
        #pragma unroll
        for (int q = 0; q < 15; ++q) {
            int h = wv * 15 + q;
            v2f acc2 = {0.f, 0.f};
            #pragma unroll
            for (int z = 0; z < 5; ++z)
                acc2 = FMA2(av2[z], *(const v2f*)(w_c1 + h * AD + 2 * z), acc2);
            float acc = acc2.x + acc2.y + b_c1[h];
            hid_s[h * 65 + lane] = fmaxf(acc, 0.0f);
        }
    }
    __syncthreads();   // bar1: logits + hidden visible

    // softmax -> coef_t (wave 0; other waves proceed to control)
    if (tid < 64) {
        float v[NB];
        float mx = -1e30f;
        #pragma unroll
        for (int k = 0; k < NB; ++k) { v[k] = lg_s[k * 64 + tid]; mx = fmaxf(mx, v[k]); }
        float sm = 0.0f;
        #pragma unroll
        for (int k = 0; k < NB; ++k) { v[k] = __expf(v[k] - mx); sm += v[k]; }
        float inv = 1.0f / sm;
        #pragma unroll
        for (int k = 0; k < NB; ++k) ws[WS_COEF + k * BATCH + b0 + tid] = v[k] * inv;
    }

    // control: row-outer, hid in registers. Wave wv owns rows [30wv, 30wv+30).
    // Per row: scalar v2f accumulator over 30 packed FMAs; w_c2 row is
    // wave-uniform contiguous 240 B -> batched s_load. No live arrays across
    // iterations -> no scratch.
    {
        v2f hv2[30];                                   // 60 VGPRs, static idx
        #pragma unroll
        for (int z = 0; z < 30; ++z) {
            float x0 = hid_s[(2 * z) * 65 + lane];     // lane-stride-1
            float x1 = hid_s[(2 * z + 1) * 65 + lane];
            hv2[z] = (v2f){x0, x1};
        }
        #pragma unroll 2
        for (int q = 0; q < 30; ++q) {
            const int o = wv * 30 + q;
            const float* wr = w_c2 + o * H;            // uniform -> s_load
            v2f acc2 = {0.f, 0.f};
            #pragma unroll
            for (int z = 0; z < 30; ++z)
                acc2 = FMA2(hv2[z], *(const v2f*)(wr + 2 * z), acc2);
            ws[WS_CTRL + o * BATCH + b0 + lane] = acc2.x + acc2.y + b_c2[o];
        }
    }
}

// ---------------------------------------------------------------------------
// Main kernel (round-7 proven core): banded predict. Per-batch MLP results
// come from ws as coalesced loads; mixing weights via uniform scalar loads.
// ---------------------------------------------------------------------------
__global__ __launch_bounds__(256, 4) void k_main(
    const float* __restrict__ pm, const float* __restrict__ cu,
    const float* __restrict__ cl, const float* __restrict__ cs,
    const float* __restrict__ log_noise,
    const float* __restrict__ ws,        // tmbg / coef_t / ctrl_t
    float* __restrict__ out)
{
    __shared__ __align__(16) float vsb[VS_FLOATS];   // 20.8 KB only

    const int tid  = threadIdx.x;
    const int lane = tid & 63;
    const int wv   = __builtin_amdgcn_readfirstlane(tid >> 6);

    // XCD-grouped swizzle: the 8 rg-blocks of one bg share one XCD's L2.
    const int bid  = blockIdx.x;            // 1024 = 8 XCDs * 128
    const int xcd  = bid & 7;
    const int slot = bid >> 3;              // 0..127
    const int bg   = xcd * 16 + (slot >> 3);
    const int rg   = slot & 7;
    const int b0   = bg * 64;
    const int i0   = rg * RG_ROWS;
    const int b    = b0 + lane;

    const float* coef_t = ws + WS_COEF;
    const float* ctrl_t = ws + WS_CTRL;

    // ---------------- issue ALL global loads up front (T14) ----------------
    float cf[NB];
    #pragma unroll
    for (int k = 0; k < NB; ++k) cf[k] = coef_t[k * BATCH + b];   // coalesced

    const int r0g = i0 + 2 * wv;
    const int c0  = (r0g < LOD) ? r0g : LOD - 1;        // rg7/wv3 clamp
    const int c1  = (r0g + 1 < LOD) ? r0g + 1 : LOD - 1;
    float ctl0 = ctrl_t[c0 * BATCH + b];                 // coalesced
    float ctl1 = ctrl_t[c1 * BATCH + b];
    float ctl2 = ctrl_t[(LOD + c0) * BATCH + b];
    float ctl3 = ctrl_t[(LOD + c1) * BATCH + b];

    float vr[20];
    {
        const int jj  = tid & 15;
        const int j   = i0 - BW + jj;
        const bool jok = (j >= 0) && (j < LOD);
        #pragma unroll
        for (int z = 0; z < 20; ++z) {
            const int idx = z * 256 + tid;
            const int blc = (idx >> 4) & 63;
            const int bb  = b0 + blc;
            float val = 0.0f;
            if (jok) {
                const int v = z >> 2;                  // compile-time per z
                if (v == 0)      val = pm[bb * LSD + j];
                else if (v == 1) val = pm[bb * LSD + LOD + j];
                else if (v == 2) val = cu[bb * LOD + j];
                else if (v == 3) val = cl[bb * LOD + j];
                else             val = cs[bb * LOD + j];
            }
            vr[z] = val;
        }
    }

    // ---------------- vs LDS writes ----------------------------------------
    {
        const int jj = tid & 15;
        #pragma unroll
        for (int z = 0; z < 20; ++z) {
            const int idx = z * 256 + tid;
            const int blc = (idx >> 4) & 63;
            vsb[(z >> 2) * VSV + jj * VSJ + blc] = vr[z];   // 2-way alias: free
        }
    }
    __syncthreads();   // bar1: vs staged

    // ---------------- mixing (scalar loads) + banded products --------------
    float onm[2], onl[2], ouv[2], olv[2], osv[2];
    #pragma unroll
    for (int rr = 0; rr < 2; ++rr) {
        const int riu = 2 * wv + rr;                    // wave-uniform
        const int iu  = i0 + riu;
        const int iuc = (iu < LOD) ? iu : LOD - 1;      // rg7: garbage, skipped

        const float* tpg = ws + (size_t)iuc * TMBG_STRIDE;
        v2f t2[14];
        #pragma unroll
        for (int z = 0; z < 14; ++z) t2[z] = (v2f){0.f, 0.f};
        #pragma unroll
        for (int k = 0; k < NB; ++k) {
            v2f c2 = {cf[k], cf[k]};                    // splat: free via op_sel
            #pragma unroll
            for (int jo = 0; jo < 7; ++jo) {
                v2f w01 = *(const v2f*)(tpg + k * 28 + jo * 4);      // s_load
                v2f w23 = *(const v2f*)(tpg + k * 28 + jo * 4 + 2);  // s_load
                t2[2 * jo]     = FMA2(c2, w01, t2[2 * jo]);
                t2[2 * jo + 1] = FMA2(c2, w23, t2[2 * jo + 1]);
            }
        }
        t2[6].x += 1.0f;     // + eye on t11 at jo == 3 (m=0)
        t2[7].y += 1.0f;     // + eye on t22 at jo == 3 (m=3)

        float nmu = 0.f, nml = 0.f, ncuv = 0.f, nclv = 0.f, ncsv = 0.f;
        #pragma unroll
        for (int jo = 0; jo < 7; ++jo) {
            const int jj = riu + jo;                    // 0..13 < NJJ
            float m_ = vsb[0 * VSV + jj * VSJ + lane];
            float n_ = vsb[1 * VSV + jj * VSJ + lane];
            float u_ = vsb[2 * VSV + jj * VSJ + lane];
            float l_ = vsb[3 * VSV + jj * VSJ + lane];
            float s_ = vsb[4 * VSV + jj * VSJ + lane];
            float A  = t2[2 * jo].x,     Bv = t2[2 * jo].y;
            float C  = t2[2 * jo + 1].x, D  = t2[2 * jo + 1].y;
            nmu = fmaf(A, m_, nmu);  nmu = fmaf(Bv, n_, nmu);
            nml = fmaf(C, m_, nml);  nml = fmaf(D, n_, nml);
            float e1 = fmaf(Bv, s_, A * u_);
            float e2 = fmaf(Bv, l_, A * s_);
            float f1 = fmaf(D, s_, C * u_);
            float f2 = fmaf(D, l_, C * s_);
            ncuv = fmaf(A, e1, ncuv);  ncuv = fmaf(Bv, e2, ncuv);
            nclv = fmaf(C, f1, nclv);  nclv = fmaf(D, f2, nclv);
            ncsv = fmaf(C, e1, ncsv);  ncsv = fmaf(D, e2, ncsv);
        }
        ncuv += elup1f(log_noise[iuc]);
        nclv += elup1f(log_noise[LOD + iuc]);
        nmu  += (rr == 0) ? ctl0 : ctl1;
        nml  += (rr == 0) ? ctl2 : ctl3;
        onm[rr] = nmu; onl[rr] = nml; ouv[rr] = ncuv; olv[rr] = nclv; osv[rr] = ncsv;
    }
    __syncthreads();   // bar2: all vs reads done -> overlay ost

    // ---------------- ost staging (overlays vs) + float4 flush -------------
    float* ost = vsb;
    #pragma unroll
    for (int rr = 0; rr < 2; ++rr) {
        const int ri = 2 * wv + rr;
        ost[0 * OST_PLANE + ri * 65 + lane] = onm[rr];
        ost[1 * OST_PLANE + ri * 65 + lane] = onl[rr];
        ost[2 * OST_PLANE + ri * 65 + lane] = ouv[rr];
        ost[3 * OST_PLANE + ri * 65 + lane] = olv[rr];
        ost[4 * OST_PLANE + ri * 65 + lane] = osv[rr];
    }
    __syncthreads();   // bar3

    // float4 flush: 640 stores total, 16B-aligned (i0 % 8 == 0)
    for (int idx = tid; idx < 5 * 64 * 2; idx += 256) {
        int q   = idx & 1;
        int blc = (idx >> 1) & 63;
        int t5  = idx >> 7;
        if (i0 + q * 4 + 3 >= LOD) continue;     // only rg7, q=1
        int bb = b0 + blc;
        int ro = q * 4;
        float4 v;
        v.x = ost[t5 * OST_PLANE + (ro + 0) * 65 + blc];
        v.y = ost[t5 * OST_PLANE + (ro + 1) * 65 + blc];
        v.z = ost[t5 * OST_PLANE + (ro + 2) * 65 + blc];
        v.w = ost[t5 * OST_PLANE + (ro + 3) * 65 + blc];
        float* bp;
        if (t5 == 0)      bp = out + bb * LSD + i0;
        else if (t5 == 1) bp = out + bb * LSD + LOD + i0;
        else if (t5 == 2) bp = out + NM_SZ + bb * LOD + i0;
        else if (t5 == 3) bp = out + NM_SZ + NC_SZ + bb * LOD + i0;
        else              bp = out + NM_SZ + 2 * NC_SZ + bb * LOD + i0;
        *(float4*)(bp + ro) = v;
    }
}

extern "C" void kernel_launch(void* const* d_in, const int* in_sizes, int n_in,
                              void* d_out, int out_size, void* d_ws, size_t ws_size,
                              hipStream_t stream) {
    (void)in_sizes; (void)n_in; (void)out_size; (void)ws_size;
    const float* pm        = (const float*)d_in[0];
    const float* cu        = (const float*)d_in[1];
    const float* cl        = (const float*)d_in[2];
    const float* cs        = (const float*)d_in[3];
    const float* action    = (const float*)d_in[4];
    const float* tm11      = (const float*)d_in[5];
    const float* tm12      = (const float*)d_in[6];
    const float* tm21      = (const float*)d_in[7];
    const float* tm22      = (const float*)d_in[8];
    const float* log_noise = (const float*)d_in[9];
    const float* w_coef    = (const float*)d_in[10];
    const float* b_coef    = (const float*)d_in[11];
    const float* w_c1      = (const float*)d_in[12];
    const float* b_c1      = (const float*)d_in[13];
    const float* w_c2      = (const float*)d_in[14];
    const float* b_c2      = (const float*)d_in[15];

    float* ws = (float*)d_ws;   // 1132800 floats = 4.53 MB

    hipLaunchKernelGGL(k_prep, dim3(128 + TMBG_FLOATS / 256), dim3(256), 0, stream,
                       pm, action, tm11, tm12, tm21, tm22,
                       w_coef, b_coef, w_c1, b_c1, w_c2, b_c2, ws);

    hipLaunchKernelGGL(k_main, dim3(1024), dim3(256), 0, stream,
                       pm, cu, cl, cs, log_noise, ws, (float*)d_out);
}